// Round 1
// baseline (356.620 us; speedup 1.0000x reference)
//
#include <hip/hip_runtime.h>
#include <hip/hip_bf16.h>

#define W_OUT 768
#define H_OUT 768
#define N_BOXES 128
#define STRIDE 2.0f

// One block per output row. Boxes cached in LDS; 128-bit row-intersection
// mask built with two wave-wide ballots; per-pixel loop iterates only set
// bits. count==1 pixels atomically max their conf into scores[owner]
// (uint-bit compare is order-preserving for non-negative floats).
__global__ void box_score_kernel(const float* __restrict__ conf,
                                 const float* __restrict__ boxes,
                                 float* __restrict__ scores) {
    __shared__ float4 sbox[N_BOXES];
    __shared__ unsigned long long rowmask_lds[2];

    const int tid = threadIdx.x;
    const int y = blockIdx.x;

    // Stage boxes: 128 threads load one box each (coalesced float4).
    if (tid < N_BOXES) {
        const float4* b4 = (const float4*)boxes;
        sbox[tid] = b4[tid];
    }
    __syncthreads();

    const float py = (y + 0.5f) * STRIDE;

    // Row mask: waves 0 and 1 cover boxes 0-63 and 64-127. All 64 lanes of
    // each wave are active (tid<128), so ballot bit i == box (wave*64 + i).
    if (tid < 2 * 64) {
        float4 b = sbox[tid];
        bool valid = (b.z - b.x) * (b.w - b.y) > 0.0f;
        bool iny = valid && (py >= b.y) && (py <= b.w);
        unsigned long long m = __ballot(iny);
        if ((tid & 63) == 0) rowmask_lds[tid >> 6] = m;
    }
    __syncthreads();

    const unsigned long long rm0 = rowmask_lds[0];
    const unsigned long long rm1 = rowmask_lds[1];

    for (int x = tid; x < W_OUT; x += blockDim.x) {
        const float px = (x + 0.5f) * STRIDE;
        int cnt = 0;
        int owner = -1;

        unsigned long long m = rm0;
        while (m) {
            int b = __ffsll(m) - 1;
            m &= m - 1;
            float4 bb = sbox[b];                 // wave-uniform b -> LDS broadcast
            if (px >= bb.x && px <= bb.z) {
                cnt++;
                if (owner < 0) owner = b;
            }
        }
        m = rm1;
        while (m) {
            int b = __ffsll(m) - 1;
            m &= m - 1;
            float4 bb = sbox[64 + b];
            if (px >= bb.x && px <= bb.z) {
                cnt++;
                if (owner < 0) owner = 64 + b;
            }
        }

        if (cnt == 1) {
            float c = conf[y * W_OUT + x];
            atomicMax((unsigned int*)&scores[owner], __float_as_uint(c));
        }
    }
}

extern "C" void kernel_launch(void* const* d_in, const int* in_sizes, int n_in,
                              void* d_out, int out_size, void* d_ws, size_t ws_size,
                              hipStream_t stream) {
    const float* conf = (const float*)d_in[0];     // (1, 768, 768) f32
    const float* boxes = (const float*)d_in[1];    // (128, 4) f32
    float* scores = (float*)d_out;                 // (128,) f32

    // Zero scores every call: harness poisons d_out once (0xAA) and never
    // re-poisons; atomicMax needs a 0 floor. Async memset is capture-safe.
    hipMemsetAsync(scores, 0, N_BOXES * sizeof(float), stream);

    box_score_kernel<<<H_OUT, 256, 0, stream>>>(conf, boxes, scores);
}

// Round 2
// 29.318 us; speedup vs baseline: 12.1640x; 12.1640x over previous
//
#include <hip/hip_runtime.h>
#include <hip/hip_bf16.h>

#define W_OUT 768
#define H_OUT 768
#define N_BOXES 128
#define STRIDE 2.0f

// One block per box b. A pixel contributes to scores[b] iff box b contains it
// and NO other valid box contains it (count==1 forces owner==b when b is the
// unique container). Each block scans only its own box's rectangle, tests the
// (few) rect-intersecting other boxes from an LDS list, block-reduces the max
// conf, and does one plain store. Zero global atomics.
__global__ void box_score_kernel(const float* __restrict__ conf,
                                 const float* __restrict__ boxes,
                                 float* __restrict__ scores) {
    __shared__ float4 sbox[N_BOXES];
    __shared__ float4 ovl[N_BOXES];
    __shared__ int novl;
    __shared__ float wmax[4];

    const int tid = threadIdx.x;
    const int b = blockIdx.x;

    if (tid < N_BOXES) sbox[tid] = ((const float4*)boxes)[tid];
    if (tid == 0) novl = 0;
    __syncthreads();

    const float4 me = sbox[b];
    const bool mevalid = (me.z - me.x) * (me.w - me.y) > 0.0f;
    if (!mevalid) {
        if (tid == 0) scores[b] = 0.0f;   // invalid box -> empty mask -> 0
        return;
    }

    // Overlap candidates: valid boxes j!=b whose continuous rect intersects
    // ours (superset of "shares a grid pixel with us").
    if (tid < N_BOXES && tid != b) {
        float4 o = sbox[tid];
        bool v = (o.z - o.x) * (o.w - o.y) > 0.0f;
        if (v && o.x <= me.z && o.z >= me.x && o.y <= me.w && o.w >= me.y) {
            int idx = atomicAdd(&novl, 1);  // LDS atomic, order-irrelevant set
            ovl[idx] = o;
        }
    }
    __syncthreads();
    const int n = novl;

    // Conservative integer pixel bounds; exact float predicate applied inside.
    int x0 = max(0, (int)floorf(me.x * 0.5f - 0.5f) - 1);
    int x1 = min(W_OUT - 1, (int)ceilf(me.z * 0.5f) + 1);
    int y0 = max(0, (int)floorf(me.y * 0.5f - 0.5f) - 1);
    int y1 = min(H_OUT - 1, (int)ceilf(me.w * 0.5f) + 1);
    const int w = x1 - x0 + 1;
    const int h = y1 - y0 + 1;

    float lmax = 0.0f;
    for (int i = tid; i < w * h; i += blockDim.x) {
        const int xx = x0 + (i % w);
        const int yy = y0 + (i / w);
        const float px = (xx + 0.5f) * STRIDE;   // bit-exact vs reference
        const float py = (yy + 0.5f) * STRIDE;
        if (px < me.x || px > me.z || py < me.y || py > me.w) continue;
        bool excl = true;
        for (int j = 0; j < n; ++j) {
            float4 o = ovl[j];
            if (px >= o.x && px <= o.z && py >= o.y && py <= o.w) {
                excl = false;
                break;
            }
        }
        if (excl) lmax = fmaxf(lmax, conf[yy * W_OUT + xx]);
    }

    // Block max-reduce: wave shuffle then cross-wave via LDS.
    for (int off = 32; off > 0; off >>= 1)
        lmax = fmaxf(lmax, __shfl_down(lmax, off));
    if ((tid & 63) == 0) wmax[tid >> 6] = lmax;
    __syncthreads();
    if (tid == 0) {
        scores[b] = fmaxf(fmaxf(wmax[0], wmax[1]), fmaxf(wmax[2], wmax[3]));
    }
}

extern "C" void kernel_launch(void* const* d_in, const int* in_sizes, int n_in,
                              void* d_out, int out_size, void* d_ws, size_t ws_size,
                              hipStream_t stream) {
    const float* conf = (const float*)d_in[0];     // (1, 768, 768) f32
    const float* boxes = (const float*)d_in[1];    // (128, 4) f32
    float* scores = (float*)d_out;                 // (128,) f32

    box_score_kernel<<<N_BOXES, 256, 0, stream>>>(conf, boxes, scores);
}